// Round 21
// baseline (70.647 us; speedup 1.0000x reference)
//
#include <hip/hip_runtime.h>

#define TT 8192
#define CC 512

typedef unsigned short u16;
typedef unsigned int u32;
typedef __attribute__((ext_vector_type(8))) short bf16x8;
typedef __attribute__((ext_vector_type(4))) float f32x4;

#define VMCNT0() asm volatile("s_waitcnt vmcnt(0)" ::: "memory")
#define LGKM0()  asm volatile("s_waitcnt lgkmcnt(0)" ::: "memory")

__device__ __forceinline__ u16 f2bf(float f) {
    u32 u = __float_as_uint(f);
    return (u16)((u + 0x7FFFu + ((u >> 16) & 1u)) >> 16);
}

__device__ __forceinline__ void gld16(const u16* g, u16* l) {
    __builtin_amdgcn_global_load_lds(
        (const __attribute__((address_space(1))) u32*)g,
        (__attribute__((address_space(3))) u32*)l, 16, 0, 0);
}

// ---- Kernel 1: LN -> xx (bf16), weight transposes (q-cols pre-scaled 1/8), xe -> xeb ----
__global__ void lnw_kernel(const float* __restrict__ x,
                           const float* __restrict__ scale,
                           const float* __restrict__ bias,
                           const float* __restrict__ Wq,
                           const float* __restrict__ Wk,
                           const float* __restrict__ Wv,
                           const float* __restrict__ xe,
                           u16* __restrict__ xx,
                           u16* __restrict__ wqkt,
                           u16* __restrict__ wvt,
                           u16* __restrict__ xeb) {
    int b = blockIdx.x;
    if (b < 2048) {
        int row = b * 4 + (threadIdx.x >> 6);
        int l = threadIdx.x & 63;
        const float4* xr = (const float4*)(x + (size_t)row * CC);
        float4 a = xr[l * 2], c = xr[l * 2 + 1];
        float s = a.x + a.y + a.z + a.w + c.x + c.y + c.z + c.w;
        float q = a.x*a.x + a.y*a.y + a.z*a.z + a.w*a.w
                + c.x*c.x + c.y*c.y + c.z*c.z + c.w*c.w;
        #pragma unroll
        for (int m = 1; m < 64; m <<= 1) {
            s += __shfl_xor(s, m, 64);
            q += __shfl_xor(q, m, 64);
        }
        float mu = s * (1.0f / CC);
        float var = q * (1.0f / CC) - mu * mu;
        float rs = rsqrtf(var + 1e-5f);
        const float4* sc4 = (const float4*)scale;
        const float4* bi4 = (const float4*)bias;
        float4 s1 = sc4[l * 2], s2 = sc4[l * 2 + 1];
        float4 b1 = bi4[l * 2], b2 = bi4[l * 2 + 1];
        bf16x8 o;
        o[0] = (short)f2bf((a.x - mu) * rs * s1.x + b1.x);
        o[1] = (short)f2bf((a.y - mu) * rs * s1.y + b1.y);
        o[2] = (short)f2bf((a.z - mu) * rs * s1.z + b1.z);
        o[3] = (short)f2bf((a.w - mu) * rs * s1.w + b1.w);
        o[4] = (short)f2bf((c.x - mu) * rs * s2.x + b2.x);
        o[5] = (short)f2bf((c.y - mu) * rs * s2.y + b2.y);
        o[6] = (short)f2bf((c.z - mu) * rs * s2.z + b2.z);
        o[7] = (short)f2bf((c.w - mu) * rs * s2.w + b2.w);
        *(bf16x8*)(xx + (size_t)row * CC + l * 8) = o;
    } else if (b < 3328) {
        int tid = (b - 2048) * 256 + threadIdx.x;   // 0 .. 327679
        if (tid < 65536) {
            int c = tid >> 9, k = tid & 511;
            float w = (c < 64) ? Wq[k * 64 + c] * 0.125f : Wk[k * 64 + (c - 64)];
            wqkt[tid] = f2bf(w);
        } else {
            int i = tid - 65536;
            int c = i >> 9, k = i & 511;
            wvt[i] = f2bf(Wv[k * 512 + c]);
        }
    } else {
        size_t i = (size_t)(b - 3328) * 2048 + (size_t)threadIdx.x * 8;
        float4 a = *(const float4*)(xe + i);
        float4 c = *(const float4*)(xe + i + 4);
        bf16x8 o;
        o[0] = (short)f2bf(a.x); o[1] = (short)f2bf(a.y);
        o[2] = (short)f2bf(a.z); o[3] = (short)f2bf(a.w);
        o[4] = (short)f2bf(c.x); o[5] = (short)f2bf(c.y);
        o[6] = (short)f2bf(c.z); o[7] = (short)f2bf(c.w);
        *(bf16x8*)(xeb + i) = o;
    }
}

// ---- Kernel 2: staged GEMM. blocks 0..63: qk = xx@[Wq/8|Wk] (+kt); 64..319: vT = (xeb@Wv)^T ----
__global__ __launch_bounds__(512, 4) void qkv_gemm_kernel(const u16* __restrict__ xx,
                                                          const u16* __restrict__ wqkt,
                                                          const u16* __restrict__ xeb,
                                                          const u16* __restrict__ wvt,
                                                          u16* __restrict__ qk,
                                                          u16* __restrict__ kt,
                                                          u16* __restrict__ vt) {
    extern __shared__ u16 smem[];      // A: 2x8192 u16 @0 ; B: 2x8192 u16 @16384 ; tl aliases @0

    const int tid = threadIdx.x;
    const int w = tid >> 6, l = tid & 63;
    const int l15 = l & 15, g = l >> 4;
    const int wr = w >> 2, wc = w & 3;

    const bool isqk = blockIdx.x < 64;
    int r0, c0;
    const u16 *Asrc, *Bsrc;
    if (isqk) { r0 = blockIdx.x * 128; c0 = 0; Asrc = xx; Bsrc = wqkt; }
    else {
        int b2 = blockIdx.x - 64;
        r0 = (b2 >> 2) * 128; c0 = (b2 & 3) * 128; Asrc = xeb; Bsrc = wvt;
    }

    const int drow = tid >> 3, sl = tid & 7;
    #define A_DMA(KK, B) { \
        _Pragma("unroll") \
        for (int i = 0; i < 2; ++i) { \
            int r = i * 64 + drow; \
            gld16(Asrc + (size_t)(r0 + r) * CC + (KK) * 64 + ((sl ^ (r & 7)) << 3), \
                  smem + (B) * 8192 + r * 64 + sl * 8); \
        } }
    #define B_DMA(KK, B) { \
        _Pragma("unroll") \
        for (int i = 0; i < 2; ++i) { \
            int r = i * 64 + drow; \
            gld16(Bsrc + (size_t)(c0 + r) * CC + (KK) * 64 + ((sl ^ (r & 7)) << 3), \
                  smem + 16384 + (B) * 8192 + r * 64 + sl * 8); \
        } }

    f32x4 acc[4][2];
    #pragma unroll
    for (int m = 0; m < 4; ++m)
        #pragma unroll
        for (int n = 0; n < 2; ++n) acc[m][n] = (f32x4){0.f, 0.f, 0.f, 0.f};

    A_DMA(0, 0); B_DMA(0, 0);

    int cur = 0;
    for (int kk = 0; kk < 8; ++kk) {
        VMCNT0();
        LGKM0();
        __builtin_amdgcn_s_barrier();
        if (kk < 7) { A_DMA(kk + 1, cur ^ 1); B_DMA(kk + 1, cur ^ 1); }

        const u16* Ab = smem + cur * 8192;
        const u16* Bb = smem + 16384 + cur * 8192;
        __builtin_amdgcn_s_setprio(1);
        #pragma unroll
        for (int ka = 0; ka < 2; ++ka) {
            bf16x8 af[4], bfr[2];
            #pragma unroll
            for (int Mt = 0; Mt < 4; ++Mt) {
                int r = wr * 64 + Mt * 16 + l15;
                int ph = (ka * 4 + g) ^ (r & 7);
                af[Mt] = *(const bf16x8*)&Ab[r * 64 + ph * 8];
            }
            #pragma unroll
            for (int Nt = 0; Nt < 2; ++Nt) {
                int c = wc * 32 + Nt * 16 + l15;
                int ph = (ka * 4 + g) ^ (c & 7);
                bfr[Nt] = *(const bf16x8*)&Bb[c * 64 + ph * 8];
            }
            #pragma unroll
            for (int Mt = 0; Mt < 4; ++Mt)
                #pragma unroll
                for (int Nt = 0; Nt < 2; ++Nt)
                    acc[Mt][Nt] = __builtin_amdgcn_mfma_f32_16x16x32_bf16(af[Mt], bfr[Nt], acc[Mt][Nt], 0, 0, 0);
        }
        __builtin_amdgcn_s_setprio(0);
        cur ^= 1;
    }

    if (isqk) {
        #pragma unroll
        for (int Mt = 0; Mt < 4; ++Mt) {
            #pragma unroll
            for (int Nt = 0; Nt < 2; ++Nt) {
                int col = wc * 32 + Nt * 16 + l15;
                #pragma unroll
                for (int jj = 0; jj < 4; ++jj) {
                    int row = wr * 64 + Mt * 16 + g * 4 + jj;
                    qk[(size_t)(r0 + row) * 128 + col] = f2bf(acc[Mt][Nt][jj]);
                }
            }
        }
        __syncthreads();
        u16* tl = smem;                     // [64 a][136]
        if (wc >= 2) {
            #pragma unroll
            for (int Mt = 0; Mt < 4; ++Mt) {
                #pragma unroll
                for (int Nt = 0; Nt < 2; ++Nt) {
                    int a = (wc - 2) * 32 + Nt * 16 + l15;
                    #pragma unroll
                    for (int jj = 0; jj < 4; ++jj) {
                        int row = wr * 64 + Mt * 16 + g * 4 + jj;
                        tl[a * 136 + row] = f2bf(acc[Mt][Nt][jj]);
                    }
                }
            }
        }
        __syncthreads();
        #pragma unroll
        for (int i = 0; i < 2; ++i) {
            int chunk = i * 512 + tid;      // 0..1023
            int a = chunk >> 4, r8 = chunk & 15;
            *(bf16x8*)(kt + (size_t)a * TT + r0 + r8 * 8) = *(const bf16x8*)&tl[a * 136 + r8 * 8];
        }
    } else {
        __syncthreads();
        u16* tl = smem;                     // [128 c][136]
        #pragma unroll
        for (int Mt = 0; Mt < 4; ++Mt) {
            #pragma unroll
            for (int Nt = 0; Nt < 2; ++Nt) {
                int col = wc * 32 + Nt * 16 + l15;
                #pragma unroll
                for (int jj = 0; jj < 4; ++jj) {
                    int row = wr * 64 + Mt * 16 + g * 4 + jj;
                    tl[col * 136 + row] = f2bf(acc[Mt][Nt][jj]);
                }
            }
        }
        __syncthreads();
        #pragma unroll
        for (int i = 0; i < 4; ++i) {
            int chunk = i * 512 + tid;      // 0..2047
            int c = chunk >> 4, r8 = chunk & 15;
            *(bf16x8*)(vt + (size_t)(c0 + c) * TT + r0 + r8 * 8) = *(const bf16x8*)&tl[c * 136 + r8 * 8];
        }
    }
    #undef A_DMA
    #undef B_DMA
}

// ---- Kernel 3 (fused gkv+scanA): per group g (8 m's), H[m] tiles + Asum[g] in regs ----
// block = (g 0..7, cs 0..7): c-slice of 64 cols, all 64 a. 8 waves: (w>>1)=c-16-quarter, (w&1)=a-half.
__global__ __launch_bounds__(512) void gkvA_kernel(const u16* __restrict__ vt,
                                                   const u16* __restrict__ kt,
                                                   float* __restrict__ H,
                                                   float* __restrict__ Asum) {
    int g = blockIdx.x >> 3, cs = blockIdx.x & 7;
    int w = threadIdx.x >> 6, l = threadIdx.x & 63;
    int l15 = l & 15, g16 = l >> 4;
    int c0 = cs * 64 + (w >> 1) * 16;
    int a0 = (w & 1) * 32;

    f32x4 asum[2];
    asum[0] = (f32x4){0.f, 0.f, 0.f, 0.f};
    asum[1] = (f32x4){0.f, 0.f, 0.f, 0.f};

    for (int t = 0; t < 8; ++t) {
        int m = g * 8 + t;
        f32x4 facc[2];
        facc[0] = (f32x4){0.f, 0.f, 0.f, 0.f};
        facc[1] = (f32x4){0.f, 0.f, 0.f, 0.f};
        #pragma unroll
        for (int ka = 0; ka < 4; ++ka) {
            int k = m * 128 + ka * 32 + g16 * 8;
            bf16x8 af = *(const bf16x8*)(vt + (size_t)(c0 + l15) * TT + k);
            #pragma unroll
            for (int Nt = 0; Nt < 2; ++Nt) {
                bf16x8 bfr = *(const bf16x8*)(kt + (size_t)(a0 + Nt * 16 + l15) * TT + k);
                facc[Nt] = __builtin_amdgcn_mfma_f32_16x16x32_bf16(af, bfr, facc[Nt], 0, 0, 0);
            }
        }
        float* hp = H + (size_t)m * 32768;
        #pragma unroll
        for (int Nt = 0; Nt < 2; ++Nt) {
            int a = a0 + Nt * 16 + l15;
            #pragma unroll
            for (int jj = 0; jj < 4; ++jj) {
                int c = c0 + g16 * 4 + jj;
                hp[c * 64 + a] = facc[Nt][jj];
                asum[Nt][jj] += facc[Nt][jj];
            }
        }
    }
    float* ap = Asum + (size_t)g * 32768;
    #pragma unroll
    for (int Nt = 0; Nt < 2; ++Nt) {
        int a = a0 + Nt * 16 + l15;
        #pragma unroll
        for (int jj = 0; jj < 4; ++jj) {
            int c = c0 + g16 * 4 + jj;
            ap[c * 64 + a] = asum[Nt][jj];
        }
    }
}

// ---- Kernel 4: ptb[i][e] = bf16( sum_{m<i} H[m][e] ), via group base + 8-deep serial ----
__global__ __launch_bounds__(256) void scanB_kernel(const float* __restrict__ H,
                                                    const float* __restrict__ Asum,
                                                    u16* __restrict__ ptb) {
    int idx = blockIdx.x * 256 + threadIdx.x;    // 0..262143
    int g = idx >> 15, e = idx & 32767;
    float acc = 0.f;
    for (int g2 = 0; g2 < g; ++g2) acc += Asum[(size_t)g2 * 32768 + e];
    ptb[(size_t)(8 * g) * 32768 + e] = f2bf(acc);
    #pragma unroll
    for (int t = 1; t < 8; ++t) {
        acc += H[(size_t)(8 * g + t - 1) * 32768 + e];
        ptb[(size_t)(8 * g + t) * 32768 + e] = f2bf(acc);
    }
}

// ---- Kernel 5: out = x + Q_i @ P_i + tril(Q_i K_diag^T) @ V_diag ; single-shot, 1 barrier ----
__global__ __launch_bounds__(512) void out_kernel(const u16* __restrict__ qk,
                                                  const u16* __restrict__ ptb,
                                                  const u16* __restrict__ vt,
                                                  const float* __restrict__ x,
                                                  float* __restrict__ out) {
    __shared__ u16 Slds[128 * 128];   // [r][128 s], 16-slot XOR swizzle, 32KB

    const int tid = threadIdx.x;
    const int w = tid >> 6, l = tid & 63;
    const int l15 = l & 15, g = l >> 4;
    const int wr = w >> 2, wcol = w & 3;

    const int rt = (int)blockIdx.x >> 2;
    const int cb = (int)blockIdx.x & 3;

    f32x4 acc[4][2];
    #pragma unroll
    for (int m = 0; m < 4; ++m)
        #pragma unroll
        for (int n = 0; n < 2; ++n) acc[m][n] = (f32x4){0.f, 0.f, 0.f, 0.f};

    // ---- diag QK^T: wave w computes S rows [w*16, +16) x 128 s ----
    const int dq = rt * 128 + w * 16 + l15;
    const bf16x8 qa0 = *(const bf16x8*)(qk + (size_t)dq * 128 + g * 8);
    const bf16x8 qa1 = *(const bf16x8*)(qk + (size_t)dq * 128 + 32 + g * 8);
    #pragma unroll
    for (int Nt = 0; Nt < 8; ++Nt) {
        int scol = Nt * 16 + l15;
        f32x4 sacc = (f32x4){0.f, 0.f, 0.f, 0.f};
        #pragma unroll
        for (int ka = 0; ka < 2; ++ka) {
            bf16x8 kf = *(const bf16x8*)(qk + (size_t)(rt * 128 + scol) * 128 + 64 + ka * 32 + g * 8);
            sacc = __builtin_amdgcn_mfma_f32_16x16x32_bf16(ka ? qa1 : qa0, kf, sacc, 0, 0, 0);
        }
        #pragma unroll
        for (int jj = 0; jj < 4; ++jj) {
            int row = w * 16 + g * 4 + jj;
            float val = (scol > row) ? 0.f : sacc[jj];
            int slot = (scol >> 3) ^ (row & 15);
            Slds[row * 128 + slot * 8 + (scol & 7)] = f2bf(val);
        }
    }

    // ---- main: acc += Q_i @ P_i (K=64) ----
    #pragma unroll
    for (int ka = 0; ka < 2; ++ka) {
        bf16x8 qf[4], pf[2];
        #pragma unroll
        for (int Mt = 0; Mt < 4; ++Mt)
            qf[Mt] = *(const bf16x8*)(qk + (size_t)(rt * 128 + wr * 64 + Mt * 16 + l15) * 128 + ka * 32 + g * 8);
        #pragma unroll
        for (int Nt = 0; Nt < 2; ++Nt) {
            int c = cb * 128 + wcol * 32 + Nt * 16 + l15;
            pf[Nt] = *(const bf16x8*)(ptb + (size_t)rt * 32768 + c * 64 + ka * 32 + g * 8);
        }
        #pragma unroll
        for (int Mt = 0; Mt < 4; ++Mt)
            #pragma unroll
            for (int Nt = 0; Nt < 2; ++Nt)
                acc[Mt][Nt] = __builtin_amdgcn_mfma_f32_16x16x32_bf16(qf[Mt], pf[Nt], acc[Mt][Nt], 0, 0, 0);
    }

    __syncthreads();

    // ---- PV diag: acc += S(128x128) @ V_diag(128 s x cols) ----
    #pragma unroll
    for (int ks = 0; ks < 4; ++ks) {
        bf16x8 sf[4], vf[2];
        #pragma unroll
        for (int Mt = 0; Mt < 4; ++Mt) {
            int row = wr * 64 + Mt * 16 + l15;
            int slot = (ks * 4 + g) ^ (row & 15);
            sf[Mt] = *(const bf16x8*)&Slds[row * 128 + slot * 8];
        }
        #pragma unroll
        for (int Nt = 0; Nt < 2; ++Nt) {
            int c = cb * 128 + wcol * 32 + Nt * 16 + l15;
            vf[Nt] = *(const bf16x8*)(vt + (size_t)c * TT + rt * 128 + ks * 32 + g * 8);
        }
        #pragma unroll
        for (int Mt = 0; Mt < 4; ++Mt)
            #pragma unroll
            for (int Nt = 0; Nt < 2; ++Nt)
                acc[Mt][Nt] = __builtin_amdgcn_mfma_f32_16x16x32_bf16(sf[Mt], vf[Nt], acc[Mt][Nt], 0, 0, 0);
    }

    // ---- epilogue: out = x + acc ----
    #pragma unroll
    for (int Mt = 0; Mt < 4; ++Mt) {
        #pragma unroll
        for (int Nt = 0; Nt < 2; ++Nt) {
            int col = cb * 128 + wcol * 32 + Nt * 16 + l15;
            #pragma unroll
            for (int jj = 0; jj < 4; ++jj) {
                int row = rt * 128 + wr * 64 + Mt * 16 + g * 4 + jj;
                out[(size_t)row * 512 + col] = x[(size_t)row * 512 + col] + acc[Mt][Nt][jj];
            }
        }
    }
}

extern "C" void kernel_launch(void* const* d_in, const int* in_sizes, int n_in,
                              void* d_out, int out_size, void* d_ws, size_t ws_size,
                              hipStream_t stream) {
    (void)in_sizes; (void)n_in; (void)out_size; (void)ws_size;
    const float* x    = (const float*)d_in[0];
    const float* xe   = (const float*)d_in[1];
    const float* lns  = (const float*)d_in[2];
    const float* lnb  = (const float*)d_in[3];
    const float* Wq   = (const float*)d_in[4];
    const float* Wk   = (const float*)d_in[5];
    const float* Wv   = (const float*)d_in[6];
    float* out = (float*)d_out;
    char* ws = (char*)d_ws;

    size_t off_xx   = 0;                                    // bf16 [8192][512]   8 MB
    size_t off_qk   = off_xx   + (size_t)TT * CC * 2;       // bf16 [8192][128]   2 MB
    size_t off_wqkt = off_qk   + (size_t)TT * 128 * 2;      // bf16 [128][512]
    size_t off_wvt  = off_wqkt + (size_t)128 * 512 * 2;     // bf16 [512][512]
    size_t off_vt   = off_wvt  + (size_t)512 * 512 * 2;     // bf16 [512][8192]   8 MB
    size_t off_xeb  = off_vt   + (size_t)TT * CC * 2;       // bf16 [8192][512]   8 MB
    size_t off_kt   = off_xeb  + (size_t)TT * CC * 2;       // bf16 [64][8192]    1 MB
    size_t off_h    = off_kt   + (size_t)64 * TT * 2;       // f32  [64][512][64]  8.4 MB
    size_t off_as   = off_h    + (size_t)64 * 32768 * 4;    // f32  [8][32768]     1 MB
    size_t off_ptb  = off_as   + (size_t)8 * 32768 * 4;     // bf16 [64][512][64]  4.2 MB

    u16* xx   = (u16*)(ws + off_xx);
    u16* qk   = (u16*)(ws + off_qk);
    u16* wqkt = (u16*)(ws + off_wqkt);
    u16* wvt  = (u16*)(ws + off_wvt);
    u16* vt   = (u16*)(ws + off_vt);
    u16* xeb  = (u16*)(ws + off_xeb);
    u16* kt   = (u16*)(ws + off_kt);
    float* H  = (float*)(ws + off_h);
    float* As = (float*)(ws + off_as);
    u16* ptb  = (u16*)(ws + off_ptb);

    const size_t qkv_lds = 65536;   // 64 KB

    hipLaunchKernelGGL(lnw_kernel,      dim3(5376), dim3(256), 0, stream,
                       x, lns, lnb, Wq, Wk, Wv, xe, xx, wqkt, wvt, xeb);
    hipLaunchKernelGGL(qkv_gemm_kernel, dim3(320),  dim3(512), qkv_lds, stream,
                       xx, wqkt, xeb, wvt, qk, kt, vt);
    hipLaunchKernelGGL(gkvA_kernel,     dim3(64),   dim3(512), 0, stream, vt, kt, H, As);
    hipLaunchKernelGGL(scanB_kernel,    dim3(1024), dim3(256), 0, stream, H, As, ptb);
    hipLaunchKernelGGL(out_kernel,      dim3(256),  dim3(512), 0, stream, qk, ptb, vt, x, out);
}

// Round 22
// 54.296 us; speedup vs baseline: 1.3012x; 1.3012x over previous
//
#include <hip/hip_runtime.h>

#define TT 8192
#define CC 512

typedef unsigned short u16;
typedef unsigned int u32;
typedef __attribute__((ext_vector_type(8))) short bf16x8;
typedef __attribute__((ext_vector_type(4))) float f32x4;

#define VMCNT0() asm volatile("s_waitcnt vmcnt(0)" ::: "memory")
#define LGKM0()  asm volatile("s_waitcnt lgkmcnt(0)" ::: "memory")

__device__ __forceinline__ u16 f2bf(float f) {
    u32 u = __float_as_uint(f);
    return (u16)((u + 0x7FFFu + ((u >> 16) & 1u)) >> 16);
}

__device__ __forceinline__ void gld16(const u16* g, u16* l) {
    __builtin_amdgcn_global_load_lds(
        (const __attribute__((address_space(1))) u32*)g,
        (__attribute__((address_space(3))) u32*)l, 16, 0, 0);
}

// ---- Kernel 1: LN -> xx (bf16), weight transposes (q-cols pre-scaled 1/8), xe -> xeb ----
__global__ void lnw_kernel(const float* __restrict__ x,
                           const float* __restrict__ scale,
                           const float* __restrict__ bias,
                           const float* __restrict__ Wq,
                           const float* __restrict__ Wk,
                           const float* __restrict__ Wv,
                           const float* __restrict__ xe,
                           u16* __restrict__ xx,
                           u16* __restrict__ wqkt,
                           u16* __restrict__ wvt,
                           u16* __restrict__ xeb) {
    int b = blockIdx.x;
    if (b < 2048) {
        int row = b * 4 + (threadIdx.x >> 6);
        int l = threadIdx.x & 63;
        const float4* xr = (const float4*)(x + (size_t)row * CC);
        float4 a = xr[l * 2], c = xr[l * 2 + 1];
        float s = a.x + a.y + a.z + a.w + c.x + c.y + c.z + c.w;
        float q = a.x*a.x + a.y*a.y + a.z*a.z + a.w*a.w
                + c.x*c.x + c.y*c.y + c.z*c.z + c.w*c.w;
        #pragma unroll
        for (int m = 1; m < 64; m <<= 1) {
            s += __shfl_xor(s, m, 64);
            q += __shfl_xor(q, m, 64);
        }
        float mu = s * (1.0f / CC);
        float var = q * (1.0f / CC) - mu * mu;
        float rs = rsqrtf(var + 1e-5f);
        const float4* sc4 = (const float4*)scale;
        const float4* bi4 = (const float4*)bias;
        float4 s1 = sc4[l * 2], s2 = sc4[l * 2 + 1];
        float4 b1 = bi4[l * 2], b2 = bi4[l * 2 + 1];
        bf16x8 o;
        o[0] = (short)f2bf((a.x - mu) * rs * s1.x + b1.x);
        o[1] = (short)f2bf((a.y - mu) * rs * s1.y + b1.y);
        o[2] = (short)f2bf((a.z - mu) * rs * s1.z + b1.z);
        o[3] = (short)f2bf((a.w - mu) * rs * s1.w + b1.w);
        o[4] = (short)f2bf((c.x - mu) * rs * s2.x + b2.x);
        o[5] = (short)f2bf((c.y - mu) * rs * s2.y + b2.y);
        o[6] = (short)f2bf((c.z - mu) * rs * s2.z + b2.z);
        o[7] = (short)f2bf((c.w - mu) * rs * s2.w + b2.w);
        *(bf16x8*)(xx + (size_t)row * CC + l * 8) = o;
    } else if (b < 3328) {
        int tid = (b - 2048) * 256 + threadIdx.x;   // 0 .. 327679
        if (tid < 65536) {
            int c = tid >> 9, k = tid & 511;
            float w = (c < 64) ? Wq[k * 64 + c] * 0.125f : Wk[k * 64 + (c - 64)];
            wqkt[tid] = f2bf(w);
        } else {
            int i = tid - 65536;
            int c = i >> 9, k = i & 511;
            wvt[i] = f2bf(Wv[k * 512 + c]);
        }
    } else {
        size_t i = (size_t)(b - 3328) * 2048 + (size_t)threadIdx.x * 8;
        float4 a = *(const float4*)(xe + i);
        float4 c = *(const float4*)(xe + i + 4);
        bf16x8 o;
        o[0] = (short)f2bf(a.x); o[1] = (short)f2bf(a.y);
        o[2] = (short)f2bf(a.z); o[3] = (short)f2bf(a.w);
        o[4] = (short)f2bf(c.x); o[5] = (short)f2bf(c.y);
        o[6] = (short)f2bf(c.z); o[7] = (short)f2bf(c.w);
        *(bf16x8*)(xeb + i) = o;
    }
}

// ---- Kernel 2: staged GEMM. blocks 0..63: qk = xx@[Wq/8|Wk] (+kt); 64..319: vT = (xeb@Wv)^T ----
__global__ __launch_bounds__(512, 4) void qkv_gemm_kernel(const u16* __restrict__ xx,
                                                          const u16* __restrict__ wqkt,
                                                          const u16* __restrict__ xeb,
                                                          const u16* __restrict__ wvt,
                                                          u16* __restrict__ qk,
                                                          u16* __restrict__ kt,
                                                          u16* __restrict__ vt) {
    extern __shared__ u16 smem[];      // A: 2x8192 u16 @0 ; B: 2x8192 u16 @16384 ; tl aliases @0

    const int tid = threadIdx.x;
    const int w = tid >> 6, l = tid & 63;
    const int l15 = l & 15, g = l >> 4;
    const int wr = w >> 2, wc = w & 3;

    const bool isqk = blockIdx.x < 64;
    int r0, c0;
    const u16 *Asrc, *Bsrc;
    if (isqk) { r0 = blockIdx.x * 128; c0 = 0; Asrc = xx; Bsrc = wqkt; }
    else {
        int b2 = blockIdx.x - 64;
        r0 = (b2 >> 2) * 128; c0 = (b2 & 3) * 128; Asrc = xeb; Bsrc = wvt;
    }

    const int drow = tid >> 3, sl = tid & 7;
    #define A_DMA(KK, B) { \
        _Pragma("unroll") \
        for (int i = 0; i < 2; ++i) { \
            int r = i * 64 + drow; \
            gld16(Asrc + (size_t)(r0 + r) * CC + (KK) * 64 + ((sl ^ (r & 7)) << 3), \
                  smem + (B) * 8192 + r * 64 + sl * 8); \
        } }
    #define B_DMA(KK, B) { \
        _Pragma("unroll") \
        for (int i = 0; i < 2; ++i) { \
            int r = i * 64 + drow; \
            gld16(Bsrc + (size_t)(c0 + r) * CC + (KK) * 64 + ((sl ^ (r & 7)) << 3), \
                  smem + 16384 + (B) * 8192 + r * 64 + sl * 8); \
        } }

    f32x4 acc[4][2];
    #pragma unroll
    for (int m = 0; m < 4; ++m)
        #pragma unroll
        for (int n = 0; n < 2; ++n) acc[m][n] = (f32x4){0.f, 0.f, 0.f, 0.f};

    A_DMA(0, 0); B_DMA(0, 0);

    int cur = 0;
    for (int kk = 0; kk < 8; ++kk) {
        VMCNT0();
        LGKM0();
        __builtin_amdgcn_s_barrier();
        if (kk < 7) { A_DMA(kk + 1, cur ^ 1); B_DMA(kk + 1, cur ^ 1); }

        const u16* Ab = smem + cur * 8192;
        const u16* Bb = smem + 16384 + cur * 8192;
        __builtin_amdgcn_s_setprio(1);
        #pragma unroll
        for (int ka = 0; ka < 2; ++ka) {
            bf16x8 af[4], bfr[2];
            #pragma unroll
            for (int Mt = 0; Mt < 4; ++Mt) {
                int r = wr * 64 + Mt * 16 + l15;
                int ph = (ka * 4 + g) ^ (r & 7);
                af[Mt] = *(const bf16x8*)&Ab[r * 64 + ph * 8];
            }
            #pragma unroll
            for (int Nt = 0; Nt < 2; ++Nt) {
                int c = wc * 32 + Nt * 16 + l15;
                int ph = (ka * 4 + g) ^ (c & 7);
                bfr[Nt] = *(const bf16x8*)&Bb[c * 64 + ph * 8];
            }
            #pragma unroll
            for (int Mt = 0; Mt < 4; ++Mt)
                #pragma unroll
                for (int Nt = 0; Nt < 2; ++Nt)
                    acc[Mt][Nt] = __builtin_amdgcn_mfma_f32_16x16x32_bf16(af[Mt], bfr[Nt], acc[Mt][Nt], 0, 0, 0);
        }
        __builtin_amdgcn_s_setprio(0);
        cur ^= 1;
    }

    if (isqk) {
        #pragma unroll
        for (int Mt = 0; Mt < 4; ++Mt) {
            #pragma unroll
            for (int Nt = 0; Nt < 2; ++Nt) {
                int col = wc * 32 + Nt * 16 + l15;
                #pragma unroll
                for (int jj = 0; jj < 4; ++jj) {
                    int row = wr * 64 + Mt * 16 + g * 4 + jj;
                    qk[(size_t)(r0 + row) * 128 + col] = f2bf(acc[Mt][Nt][jj]);
                }
            }
        }
        __syncthreads();
        u16* tl = smem;                     // [64 a][136]
        if (wc >= 2) {
            #pragma unroll
            for (int Mt = 0; Mt < 4; ++Mt) {
                #pragma unroll
                for (int Nt = 0; Nt < 2; ++Nt) {
                    int a = (wc - 2) * 32 + Nt * 16 + l15;
                    #pragma unroll
                    for (int jj = 0; jj < 4; ++jj) {
                        int row = wr * 64 + Mt * 16 + g * 4 + jj;
                        tl[a * 136 + row] = f2bf(acc[Mt][Nt][jj]);
                    }
                }
            }
        }
        __syncthreads();
        #pragma unroll
        for (int i = 0; i < 2; ++i) {
            int chunk = i * 512 + tid;      // 0..1023
            int a = chunk >> 4, r8 = chunk & 15;
            *(bf16x8*)(kt + (size_t)a * TT + r0 + r8 * 8) = *(const bf16x8*)&tl[a * 136 + r8 * 8];
        }
    } else {
        __syncthreads();
        u16* tl = smem;                     // [128 c][136]
        #pragma unroll
        for (int Mt = 0; Mt < 4; ++Mt) {
            #pragma unroll
            for (int Nt = 0; Nt < 2; ++Nt) {
                int col = wc * 32 + Nt * 16 + l15;
                #pragma unroll
                for (int jj = 0; jj < 4; ++jj) {
                    int row = wr * 64 + Mt * 16 + g * 4 + jj;
                    tl[col * 136 + row] = f2bf(acc[Mt][Nt][jj]);
                }
            }
        }
        __syncthreads();
        #pragma unroll
        for (int i = 0; i < 4; ++i) {
            int chunk = i * 512 + tid;      // 0..2047
            int c = chunk >> 4, r8 = chunk & 15;
            *(bf16x8*)(vt + (size_t)(c0 + c) * TT + r0 + r8 * 8) = *(const bf16x8*)&tl[c * 136 + r8 * 8];
        }
    }
    #undef A_DMA
    #undef B_DMA
}

// ---- Kernel 3: H[m][c][a] = sum_{s in rows [m*128,(m+1)*128)} V[s][c] K[s][a]  (f32), m=0..63 ----
__global__ __launch_bounds__(512) void gkv_kernel(const u16* __restrict__ vt,
                                                  const u16* __restrict__ kt,
                                                  float* __restrict__ H) {
    int m = blockIdx.x >> 2, cq = blockIdx.x & 3;
    int w = threadIdx.x >> 6, l = threadIdx.x & 63;
    int l15 = l & 15, g = l >> 4;
    int c0 = cq * 128 + (w >> 1) * 32;
    int a0 = (w & 1) * 32;

    f32x4 acc[2][2];
    #pragma unroll
    for (int i = 0; i < 2; ++i)
        #pragma unroll
        for (int n = 0; n < 2; ++n) acc[i][n] = (f32x4){0.f, 0.f, 0.f, 0.f};

    #pragma unroll
    for (int ka = 0; ka < 4; ++ka) {
        int k = m * 128 + ka * 32 + g * 8;
        bf16x8 af[2], bfr[2];
        #pragma unroll
        for (int Mt = 0; Mt < 2; ++Mt)
            af[Mt] = *(const bf16x8*)(vt + (size_t)(c0 + Mt * 16 + l15) * TT + k);
        #pragma unroll
        for (int Nt = 0; Nt < 2; ++Nt)
            bfr[Nt] = *(const bf16x8*)(kt + (size_t)(a0 + Nt * 16 + l15) * TT + k);
        #pragma unroll
        for (int Mt = 0; Mt < 2; ++Mt)
            #pragma unroll
            for (int Nt = 0; Nt < 2; ++Nt)
                acc[Mt][Nt] = __builtin_amdgcn_mfma_f32_16x16x32_bf16(af[Mt], bfr[Nt], acc[Mt][Nt], 0, 0, 0);
    }

    float* hp = H + (size_t)m * 32768;
    #pragma unroll
    for (int Mt = 0; Mt < 2; ++Mt) {
        #pragma unroll
        for (int Nt = 0; Nt < 2; ++Nt) {
            int a = a0 + Nt * 16 + l15;
            #pragma unroll
            for (int jj = 0; jj < 4; ++jj) {
                int c = c0 + Mt * 16 + g * 4 + jj;
                hp[c * 64 + a] = acc[Mt][Nt][jj];
            }
        }
    }
}

// ---- Kernel 4a: Asum[g][e] = sum_{t<8} H[8g+t][e],  g=0..7 ----
__global__ __launch_bounds__(256) void scanA_kernel(const float* __restrict__ H,
                                                    float* __restrict__ Asum) {
    int idx = blockIdx.x * 256 + threadIdx.x;    // 0..262143
    int g = idx >> 15, e = idx & 32767;
    float s = 0.f;
    #pragma unroll
    for (int t = 0; t < 8; ++t) s += H[(size_t)(8 * g + t) * 32768 + e];
    Asum[(size_t)g * 32768 + e] = s;
}

// ---- Kernel 4b: ptb[i][e] = bf16( sum_{m<i} H[m][e] ), via group base + 8-deep serial ----
__global__ __launch_bounds__(256) void scanB_kernel(const float* __restrict__ H,
                                                    const float* __restrict__ Asum,
                                                    u16* __restrict__ ptb) {
    int idx = blockIdx.x * 256 + threadIdx.x;    // 0..262143
    int g = idx >> 15, e = idx & 32767;
    float acc = 0.f;
    for (int g2 = 0; g2 < g; ++g2) acc += Asum[(size_t)g2 * 32768 + e];
    ptb[(size_t)(8 * g) * 32768 + e] = f2bf(acc);
    #pragma unroll
    for (int t = 1; t < 8; ++t) {
        acc += H[(size_t)(8 * g + t - 1) * 32768 + e];
        ptb[(size_t)(8 * g + t) * 32768 + e] = f2bf(acc);
    }
}

// ---- Kernel 5: out = x + Q_i @ P_i + tril(Q_i K_diag^T) @ V_diag ; single-shot, 1 barrier ----
__global__ __launch_bounds__(512) void out_kernel(const u16* __restrict__ qk,
                                                  const u16* __restrict__ ptb,
                                                  const u16* __restrict__ vt,
                                                  const float* __restrict__ x,
                                                  float* __restrict__ out) {
    __shared__ u16 Slds[128 * 128];   // [r][128 s], 16-slot XOR swizzle, 32KB

    const int tid = threadIdx.x;
    const int w = tid >> 6, l = tid & 63;
    const int l15 = l & 15, g = l >> 4;
    const int wr = w >> 2, wcol = w & 3;

    const int rt = (int)blockIdx.x >> 2;
    const int cb = (int)blockIdx.x & 3;

    f32x4 acc[4][2];
    #pragma unroll
    for (int m = 0; m < 4; ++m)
        #pragma unroll
        for (int n = 0; n < 2; ++n) acc[m][n] = (f32x4){0.f, 0.f, 0.f, 0.f};

    // ---- diag QK^T: wave w computes S rows [w*16, +16) x 128 s ----
    const int dq = rt * 128 + w * 16 + l15;
    const bf16x8 qa0 = *(const bf16x8*)(qk + (size_t)dq * 128 + g * 8);
    const bf16x8 qa1 = *(const bf16x8*)(qk + (size_t)dq * 128 + 32 + g * 8);
    #pragma unroll
    for (int Nt = 0; Nt < 8; ++Nt) {
        int scol = Nt * 16 + l15;
        f32x4 sacc = (f32x4){0.f, 0.f, 0.f, 0.f};
        #pragma unroll
        for (int ka = 0; ka < 2; ++ka) {
            bf16x8 kf = *(const bf16x8*)(qk + (size_t)(rt * 128 + scol) * 128 + 64 + ka * 32 + g * 8);
            sacc = __builtin_amdgcn_mfma_f32_16x16x32_bf16(ka ? qa1 : qa0, kf, sacc, 0, 0, 0);
        }
        #pragma unroll
        for (int jj = 0; jj < 4; ++jj) {
            int row = w * 16 + g * 4 + jj;
            float val = (scol > row) ? 0.f : sacc[jj];
            int slot = (scol >> 3) ^ (row & 15);
            Slds[row * 128 + slot * 8 + (scol & 7)] = f2bf(val);
        }
    }

    // ---- main: acc += Q_i @ P_i (K=64) ----
    #pragma unroll
    for (int ka = 0; ka < 2; ++ka) {
        bf16x8 qf[4], pf[2];
        #pragma unroll
        for (int Mt = 0; Mt < 4; ++Mt)
            qf[Mt] = *(const bf16x8*)(qk + (size_t)(rt * 128 + wr * 64 + Mt * 16 + l15) * 128 + ka * 32 + g * 8);
        #pragma unroll
        for (int Nt = 0; Nt < 2; ++Nt) {
            int c = cb * 128 + wcol * 32 + Nt * 16 + l15;
            pf[Nt] = *(const bf16x8*)(ptb + (size_t)rt * 32768 + c * 64 + ka * 32 + g * 8);
        }
        #pragma unroll
        for (int Mt = 0; Mt < 4; ++Mt)
            #pragma unroll
            for (int Nt = 0; Nt < 2; ++Nt)
                acc[Mt][Nt] = __builtin_amdgcn_mfma_f32_16x16x32_bf16(qf[Mt], pf[Nt], acc[Mt][Nt], 0, 0, 0);
    }

    __syncthreads();

    // ---- PV diag: acc += S(128x128) @ V_diag(128 s x cols) ----
    #pragma unroll
    for (int ks = 0; ks < 4; ++ks) {
        bf16x8 sf[4], vf[2];
        #pragma unroll
        for (int Mt = 0; Mt < 4; ++Mt) {
            int row = wr * 64 + Mt * 16 + l15;
            int slot = (ks * 4 + g) ^ (row & 15);
            sf[Mt] = *(const bf16x8*)&Slds[row * 128 + slot * 8];
        }
        #pragma unroll
        for (int Nt = 0; Nt < 2; ++Nt) {
            int c = cb * 128 + wcol * 32 + Nt * 16 + l15;
            vf[Nt] = *(const bf16x8*)(vt + (size_t)c * TT + rt * 128 + ks * 32 + g * 8);
        }
        #pragma unroll
        for (int Mt = 0; Mt < 4; ++Mt)
            #pragma unroll
            for (int Nt = 0; Nt < 2; ++Nt)
                acc[Mt][Nt] = __builtin_amdgcn_mfma_f32_16x16x32_bf16(sf[Mt], vf[Nt], acc[Mt][Nt], 0, 0, 0);
    }

    // ---- epilogue: out = x + acc ----
    #pragma unroll
    for (int Mt = 0; Mt < 4; ++Mt) {
        #pragma unroll
        for (int Nt = 0; Nt < 2; ++Nt) {
            int col = cb * 128 + wcol * 32 + Nt * 16 + l15;
            #pragma unroll
            for (int jj = 0; jj < 4; ++jj) {
                int row = rt * 128 + wr * 64 + Mt * 16 + g * 4 + jj;
                out[(size_t)row * 512 + col] = x[(size_t)row * 512 + col] + acc[Mt][Nt][jj];
            }
        }
    }
}

extern "C" void kernel_launch(void* const* d_in, const int* in_sizes, int n_in,
                              void* d_out, int out_size, void* d_ws, size_t ws_size,
                              hipStream_t stream) {
    (void)in_sizes; (void)n_in; (void)out_size; (void)ws_size;
    const float* x    = (const float*)d_in[0];
    const float* xe   = (const float*)d_in[1];
    const float* lns  = (const float*)d_in[2];
    const float* lnb  = (const float*)d_in[3];
    const float* Wq   = (const float*)d_in[4];
    const float* Wk   = (const float*)d_in[5];
    const float* Wv   = (const float*)d_in[6];
    float* out = (float*)d_out;
    char* ws = (char*)d_ws;

    size_t off_xx   = 0;                                    // bf16 [8192][512]   8 MB
    size_t off_qk   = off_xx   + (size_t)TT * CC * 2;       // bf16 [8192][128]   2 MB
    size_t off_wqkt = off_qk   + (size_t)TT * 128 * 2;      // bf16 [128][512]
    size_t off_wvt  = off_wqkt + (size_t)128 * 512 * 2;     // bf16 [512][512]
    size_t off_vt   = off_wvt  + (size_t)512 * 512 * 2;     // bf16 [512][8192]   8 MB
    size_t off_xeb  = off_vt   + (size_t)TT * CC * 2;       // bf16 [8192][512]   8 MB
    size_t off_kt   = off_xeb  + (size_t)TT * CC * 2;       // bf16 [64][8192]    1 MB
    size_t off_h    = off_kt   + (size_t)64 * TT * 2;       // f32  [64][512][64]  8.4 MB
    size_t off_as   = off_h    + (size_t)64 * 32768 * 4;    // f32  [8][32768]     1 MB
    size_t off_ptb  = off_as   + (size_t)8 * 32768 * 4;     // bf16 [64][512][64]  4.2 MB

    u16* xx   = (u16*)(ws + off_xx);
    u16* qk   = (u16*)(ws + off_qk);
    u16* wqkt = (u16*)(ws + off_wqkt);
    u16* wvt  = (u16*)(ws + off_wvt);
    u16* vt   = (u16*)(ws + off_vt);
    u16* xeb  = (u16*)(ws + off_xeb);
    u16* kt   = (u16*)(ws + off_kt);
    float* H  = (float*)(ws + off_h);
    float* As = (float*)(ws + off_as);
    u16* ptb  = (u16*)(ws + off_ptb);

    const size_t qkv_lds = 65536;   // 64 KB

    hipLaunchKernelGGL(lnw_kernel,      dim3(5376), dim3(256), 0, stream,
                       x, lns, lnb, Wq, Wk, Wv, xe, xx, wqkt, wvt, xeb);
    hipLaunchKernelGGL(qkv_gemm_kernel, dim3(320),  dim3(512), qkv_lds, stream,
                       xx, wqkt, xeb, wvt, qk, kt, vt);
    hipLaunchKernelGGL(gkv_kernel,      dim3(256),  dim3(512), 0, stream, vt, kt, H);
    hipLaunchKernelGGL(scanA_kernel,    dim3(1024), dim3(256), 0, stream, H, As);
    hipLaunchKernelGGL(scanB_kernel,    dim3(1024), dim3(256), 0, stream, H, As, ptb);
    hipLaunchKernelGGL(out_kernel,      dim3(256),  dim3(512), 0, stream, qk, ptb, vt, x, out);
}

// Round 23
// 54.226 us; speedup vs baseline: 1.3028x; 1.0013x over previous
//
#include <hip/hip_runtime.h>

#define TT 8192
#define CC 512

typedef unsigned short u16;
typedef unsigned int u32;
typedef __attribute__((ext_vector_type(8))) short bf16x8;
typedef __attribute__((ext_vector_type(4))) float f32x4;

#define VMCNT0() asm volatile("s_waitcnt vmcnt(0)" ::: "memory")
#define LGKM0()  asm volatile("s_waitcnt lgkmcnt(0)" ::: "memory")

__device__ __forceinline__ u16 f2bf(float f) {
    u32 u = __float_as_uint(f);
    return (u16)((u + 0x7FFFu + ((u >> 16) & 1u)) >> 16);
}

__device__ __forceinline__ void gld16(const u16* g, u16* l) {
    __builtin_amdgcn_global_load_lds(
        (const __attribute__((address_space(1))) u32*)g,
        (__attribute__((address_space(3))) u32*)l, 16, 0, 0);
}

// ---- Kernel 1: LN -> xx (bf16), weight transposes (q-cols pre-scaled 1/8), xe -> xeb ----
__global__ void lnw_kernel(const float* __restrict__ x,
                           const float* __restrict__ scale,
                           const float* __restrict__ bias,
                           const float* __restrict__ Wq,
                           const float* __restrict__ Wk,
                           const float* __restrict__ Wv,
                           const float* __restrict__ xe,
                           u16* __restrict__ xx,
                           u16* __restrict__ wqkt,
                           u16* __restrict__ wvt,
                           u16* __restrict__ xeb) {
    int b = blockIdx.x;
    if (b < 2048) {
        int row = b * 4 + (threadIdx.x >> 6);
        int l = threadIdx.x & 63;
        const float4* xr = (const float4*)(x + (size_t)row * CC);
        float4 a = xr[l * 2], c = xr[l * 2 + 1];
        float s = a.x + a.y + a.z + a.w + c.x + c.y + c.z + c.w;
        float q = a.x*a.x + a.y*a.y + a.z*a.z + a.w*a.w
                + c.x*c.x + c.y*c.y + c.z*c.z + c.w*c.w;
        #pragma unroll
        for (int m = 1; m < 64; m <<= 1) {
            s += __shfl_xor(s, m, 64);
            q += __shfl_xor(q, m, 64);
        }
        float mu = s * (1.0f / CC);
        float var = q * (1.0f / CC) - mu * mu;
        float rs = rsqrtf(var + 1e-5f);
        const float4* sc4 = (const float4*)scale;
        const float4* bi4 = (const float4*)bias;
        float4 s1 = sc4[l * 2], s2 = sc4[l * 2 + 1];
        float4 b1 = bi4[l * 2], b2 = bi4[l * 2 + 1];
        bf16x8 o;
        o[0] = (short)f2bf((a.x - mu) * rs * s1.x + b1.x);
        o[1] = (short)f2bf((a.y - mu) * rs * s1.y + b1.y);
        o[2] = (short)f2bf((a.z - mu) * rs * s1.z + b1.z);
        o[3] = (short)f2bf((a.w - mu) * rs * s1.w + b1.w);
        o[4] = (short)f2bf((c.x - mu) * rs * s2.x + b2.x);
        o[5] = (short)f2bf((c.y - mu) * rs * s2.y + b2.y);
        o[6] = (short)f2bf((c.z - mu) * rs * s2.z + b2.z);
        o[7] = (short)f2bf((c.w - mu) * rs * s2.w + b2.w);
        *(bf16x8*)(xx + (size_t)row * CC + l * 8) = o;
    } else if (b < 3328) {
        int tid = (b - 2048) * 256 + threadIdx.x;   // 0 .. 327679
        if (tid < 65536) {
            int c = tid >> 9, k = tid & 511;
            float w = (c < 64) ? Wq[k * 64 + c] * 0.125f : Wk[k * 64 + (c - 64)];
            wqkt[tid] = f2bf(w);
        } else {
            int i = tid - 65536;
            int c = i >> 9, k = i & 511;
            wvt[i] = f2bf(Wv[k * 512 + c]);
        }
    } else {
        size_t i = (size_t)(b - 3328) * 2048 + (size_t)threadIdx.x * 8;
        float4 a = *(const float4*)(xe + i);
        float4 c = *(const float4*)(xe + i + 4);
        bf16x8 o;
        o[0] = (short)f2bf(a.x); o[1] = (short)f2bf(a.y);
        o[2] = (short)f2bf(a.z); o[3] = (short)f2bf(a.w);
        o[4] = (short)f2bf(c.x); o[5] = (short)f2bf(c.y);
        o[6] = (short)f2bf(c.z); o[7] = (short)f2bf(c.w);
        *(bf16x8*)(xeb + i) = o;
    }
}

// ---- Kernel 2: staged GEMM, 512 blocks = 2/CU exactly ----
// blocks 0..255: vT = (xeb@Wv)^T tiles (M=128,N=128); blocks 256..511: qk = xx@[Wq/8|Wk] (M=32) + kt.
__global__ __launch_bounds__(512, 4) void qkv_gemm_kernel(const u16* __restrict__ xx,
                                                          const u16* __restrict__ wqkt,
                                                          const u16* __restrict__ xeb,
                                                          const u16* __restrict__ wvt,
                                                          u16* __restrict__ qk,
                                                          u16* __restrict__ kt,
                                                          u16* __restrict__ vt) {
    extern __shared__ u16 smem[];      // A: 2x8192 u16 @0 ; B: 2x8192 u16 @16384 ; tl aliases @0

    const int tid = threadIdx.x;
    const int w = tid >> 6, l = tid & 63;
    const int l15 = l & 15, g = l >> 4;
    const int wr = w >> 2, wc = w & 3;

    const bool isqk = blockIdx.x >= 256;
    int r0, c0;
    const u16 *Asrc, *Bsrc;
    if (!isqk) {
        int b2 = blockIdx.x;
        r0 = (b2 >> 2) * 128; c0 = (b2 & 3) * 128; Asrc = xeb; Bsrc = wvt;
    } else {
        r0 = (blockIdx.x - 256) * 32; c0 = 0; Asrc = xx; Bsrc = wqkt;
    }

    const int drow = tid >> 3, sl = tid & 7;
    // v: A = 128 rows (2 gld/thread). qk: A = 32 rows (1 gld/thread; rows duplicated x2, same data).
    #define A_DMA(KK, B) { \
        if (!isqk) { \
            _Pragma("unroll") \
            for (int i = 0; i < 2; ++i) { \
                int r = i * 64 + drow; \
                gld16(Asrc + (size_t)(r0 + r) * CC + (KK) * 64 + ((sl ^ (r & 7)) << 3), \
                      smem + (B) * 8192 + r * 64 + sl * 8); \
            } \
        } else { \
            int r = drow & 31; \
            gld16(Asrc + (size_t)(r0 + r) * CC + (KK) * 64 + ((sl ^ (r & 7)) << 3), \
                  smem + (B) * 8192 + r * 64 + sl * 8); \
        } }
    #define B_DMA(KK, B) { \
        _Pragma("unroll") \
        for (int i = 0; i < 2; ++i) { \
            int r = i * 64 + drow; \
            gld16(Bsrc + (size_t)(c0 + r) * CC + (KK) * 64 + ((sl ^ (r & 7)) << 3), \
                  smem + 16384 + (B) * 8192 + r * 64 + sl * 8); \
        } }

    f32x4 acc[4][2];
    #pragma unroll
    for (int m = 0; m < 4; ++m)
        #pragma unroll
        for (int n = 0; n < 2; ++n) acc[m][n] = (f32x4){0.f, 0.f, 0.f, 0.f};

    A_DMA(0, 0); B_DMA(0, 0);

    int cur = 0;
    for (int kk = 0; kk < 8; ++kk) {
        VMCNT0();
        LGKM0();
        __builtin_amdgcn_s_barrier();
        if (kk < 7) { A_DMA(kk + 1, cur ^ 1); B_DMA(kk + 1, cur ^ 1); }

        const u16* Ab = smem + cur * 8192;
        const u16* Bb = smem + 16384 + cur * 8192;
        __builtin_amdgcn_s_setprio(1);
        if (!isqk) {
            #pragma unroll
            for (int ka = 0; ka < 2; ++ka) {
                bf16x8 af[4], bfr[2];
                #pragma unroll
                for (int Mt = 0; Mt < 4; ++Mt) {
                    int r = wr * 64 + Mt * 16 + l15;
                    int ph = (ka * 4 + g) ^ (r & 7);
                    af[Mt] = *(const bf16x8*)&Ab[r * 64 + ph * 8];
                }
                #pragma unroll
                for (int Nt = 0; Nt < 2; ++Nt) {
                    int c = wc * 32 + Nt * 16 + l15;
                    int ph = (ka * 4 + g) ^ (c & 7);
                    bfr[Nt] = *(const bf16x8*)&Bb[c * 64 + ph * 8];
                }
                #pragma unroll
                for (int Mt = 0; Mt < 4; ++Mt)
                    #pragma unroll
                    for (int Nt = 0; Nt < 2; ++Nt)
                        acc[Mt][Nt] = __builtin_amdgcn_mfma_f32_16x16x32_bf16(af[Mt], bfr[Nt], acc[Mt][Nt], 0, 0, 0);
            }
        } else {
            #pragma unroll
            for (int ka = 0; ka < 2; ++ka) {
                int r = wr * 16 + l15;                 // rows 0..31
                int pha = (ka * 4 + g) ^ (r & 7);
                bf16x8 af = *(const bf16x8*)&Ab[r * 64 + pha * 8];
                #pragma unroll
                for (int Nt = 0; Nt < 2; ++Nt) {
                    int c = wc * 32 + Nt * 16 + l15;
                    int ph = (ka * 4 + g) ^ (c & 7);
                    bf16x8 bfr = *(const bf16x8*)&Bb[c * 64 + ph * 8];
                    acc[0][Nt] = __builtin_amdgcn_mfma_f32_16x16x32_bf16(af, bfr, acc[0][Nt], 0, 0, 0);
                }
            }
        }
        __builtin_amdgcn_s_setprio(0);
        cur ^= 1;
    }

    if (isqk) {
        // qk store (32 rows x 128 cols)
        #pragma unroll
        for (int Nt = 0; Nt < 2; ++Nt) {
            int col = wc * 32 + Nt * 16 + l15;
            #pragma unroll
            for (int jj = 0; jj < 4; ++jj) {
                int row = wr * 16 + g * 4 + jj;
                qk[(size_t)(r0 + row) * 128 + col] = f2bf(acc[0][Nt][jj]);
            }
        }
        __syncthreads();
        u16* tl = smem;                     // [64 a][40]
        if (wc >= 2) {
            #pragma unroll
            for (int Nt = 0; Nt < 2; ++Nt) {
                int a = (wc - 2) * 32 + Nt * 16 + l15;
                #pragma unroll
                for (int jj = 0; jj < 4; ++jj) {
                    int row = wr * 16 + g * 4 + jj;   // 0..31
                    tl[a * 40 + row] = f2bf(acc[0][Nt][jj]);
                }
            }
        }
        __syncthreads();
        if (tid < 256) {
            int a = tid >> 2, r8 = tid & 3;
            *(bf16x8*)(kt + (size_t)a * TT + r0 + r8 * 8) = *(const bf16x8*)&tl[a * 40 + r8 * 8];
        }
    } else {
        // vT store via LDS transpose (alias staging)
        __syncthreads();
        u16* tl = smem;                     // [128 c][136]
        #pragma unroll
        for (int Mt = 0; Mt < 4; ++Mt) {
            #pragma unroll
            for (int Nt = 0; Nt < 2; ++Nt) {
                int col = wc * 32 + Nt * 16 + l15;
                #pragma unroll
                for (int jj = 0; jj < 4; ++jj) {
                    int row = wr * 64 + Mt * 16 + g * 4 + jj;
                    tl[col * 136 + row] = f2bf(acc[Mt][Nt][jj]);
                }
            }
        }
        __syncthreads();
        #pragma unroll
        for (int i = 0; i < 4; ++i) {
            int chunk = i * 512 + tid;      // 0..2047
            int c = chunk >> 4, r8 = chunk & 15;
            *(bf16x8*)(vt + (size_t)(c0 + c) * TT + r0 + r8 * 8) = *(const bf16x8*)&tl[c * 136 + r8 * 8];
        }
    }
    #undef A_DMA
    #undef B_DMA
}

// ---- Kernel 3: H[m][c][a] = sum_{s in rows [m*128,(m+1)*128)} V[s][c] K[s][a]  (f32), m=0..63 ----
__global__ __launch_bounds__(512) void gkv_kernel(const u16* __restrict__ vt,
                                                  const u16* __restrict__ kt,
                                                  float* __restrict__ H) {
    int m = blockIdx.x >> 2, cq = blockIdx.x & 3;
    int w = threadIdx.x >> 6, l = threadIdx.x & 63;
    int l15 = l & 15, g = l >> 4;
    int c0 = cq * 128 + (w >> 1) * 32;
    int a0 = (w & 1) * 32;

    f32x4 acc[2][2];
    #pragma unroll
    for (int i = 0; i < 2; ++i)
        #pragma unroll
        for (int n = 0; n < 2; ++n) acc[i][n] = (f32x4){0.f, 0.f, 0.f, 0.f};

    #pragma unroll
    for (int ka = 0; ka < 4; ++ka) {
        int k = m * 128 + ka * 32 + g * 8;
        bf16x8 af[2], bfr[2];
        #pragma unroll
        for (int Mt = 0; Mt < 2; ++Mt)
            af[Mt] = *(const bf16x8*)(vt + (size_t)(c0 + Mt * 16 + l15) * TT + k);
        #pragma unroll
        for (int Nt = 0; Nt < 2; ++Nt)
            bfr[Nt] = *(const bf16x8*)(kt + (size_t)(a0 + Nt * 16 + l15) * TT + k);
        #pragma unroll
        for (int Mt = 0; Mt < 2; ++Mt)
            #pragma unroll
            for (int Nt = 0; Nt < 2; ++Nt)
                acc[Mt][Nt] = __builtin_amdgcn_mfma_f32_16x16x32_bf16(af[Mt], bfr[Nt], acc[Mt][Nt], 0, 0, 0);
    }

    float* hp = H + (size_t)m * 32768;
    #pragma unroll
    for (int Mt = 0; Mt < 2; ++Mt) {
        #pragma unroll
        for (int Nt = 0; Nt < 2; ++Nt) {
            int a = a0 + Nt * 16 + l15;
            #pragma unroll
            for (int jj = 0; jj < 4; ++jj) {
                int c = c0 + Mt * 16 + g * 4 + jj;
                hp[c * 64 + a] = acc[Mt][Nt][jj];
            }
        }
    }
}

// ---- Kernel 4a: Asum[g][e] = sum_{t<8} H[8g+t][e],  g=0..7 ----
__global__ __launch_bounds__(256) void scanA_kernel(const float* __restrict__ H,
                                                    float* __restrict__ Asum) {
    int idx = blockIdx.x * 256 + threadIdx.x;    // 0..262143
    int g = idx >> 15, e = idx & 32767;
    float s = 0.f;
    #pragma unroll
    for (int t = 0; t < 8; ++t) s += H[(size_t)(8 * g + t) * 32768 + e];
    Asum[(size_t)g * 32768 + e] = s;
}

// ---- Kernel 4b: ptb[i][e] = bf16( sum_{m<i} H[m][e] ), via group base + 8-deep serial ----
__global__ __launch_bounds__(256) void scanB_kernel(const float* __restrict__ H,
                                                    const float* __restrict__ Asum,
                                                    u16* __restrict__ ptb) {
    int idx = blockIdx.x * 256 + threadIdx.x;    // 0..262143
    int g = idx >> 15, e = idx & 32767;
    float acc = 0.f;
    for (int g2 = 0; g2 < g; ++g2) acc += Asum[(size_t)g2 * 32768 + e];
    ptb[(size_t)(8 * g) * 32768 + e] = f2bf(acc);
    #pragma unroll
    for (int t = 1; t < 8; ++t) {
        acc += H[(size_t)(8 * g + t - 1) * 32768 + e];
        ptb[(size_t)(8 * g + t) * 32768 + e] = f2bf(acc);
    }
}

// ---- Kernel 5: out = x + Q_i @ P_i + tril(Q_i K_diag^T) @ V_diag ; single-shot, 1 barrier ----
__global__ __launch_bounds__(512) void out_kernel(const u16* __restrict__ qk,
                                                  const u16* __restrict__ ptb,
                                                  const u16* __restrict__ vt,
                                                  const float* __restrict__ x,
                                                  float* __restrict__ out) {
    __shared__ u16 Slds[128 * 128];   // [r][128 s], 16-slot XOR swizzle, 32KB

    const int tid = threadIdx.x;
    const int w = tid >> 6, l = tid & 63;
    const int l15 = l & 15, g = l >> 4;
    const int wr = w >> 2, wcol = w & 3;

    const int rt = (int)blockIdx.x >> 2;
    const int cb = (int)blockIdx.x & 3;

    f32x4 acc[4][2];
    #pragma unroll
    for (int m = 0; m < 4; ++m)
        #pragma unroll
        for (int n = 0; n < 2; ++n) acc[m][n] = (f32x4){0.f, 0.f, 0.f, 0.f};

    // ---- diag QK^T: wave w computes S rows [w*16, +16) x 128 s ----
    const int dq = rt * 128 + w * 16 + l15;
    const bf16x8 qa0 = *(const bf16x8*)(qk + (size_t)dq * 128 + g * 8);
    const bf16x8 qa1 = *(const bf16x8*)(qk + (size_t)dq * 128 + 32 + g * 8);
    #pragma unroll
    for (int Nt = 0; Nt < 8; ++Nt) {
        int scol = Nt * 16 + l15;
        f32x4 sacc = (f32x4){0.f, 0.f, 0.f, 0.f};
        #pragma unroll
        for (int ka = 0; ka < 2; ++ka) {
            bf16x8 kf = *(const bf16x8*)(qk + (size_t)(rt * 128 + scol) * 128 + 64 + ka * 32 + g * 8);
            sacc = __builtin_amdgcn_mfma_f32_16x16x32_bf16(ka ? qa1 : qa0, kf, sacc, 0, 0, 0);
        }
        #pragma unroll
        for (int jj = 0; jj < 4; ++jj) {
            int row = w * 16 + g * 4 + jj;
            float val = (scol > row) ? 0.f : sacc[jj];
            int slot = (scol >> 3) ^ (row & 15);
            Slds[row * 128 + slot * 8 + (scol & 7)] = f2bf(val);
        }
    }

    // ---- main: acc += Q_i @ P_i (K=64) ----
    #pragma unroll
    for (int ka = 0; ka < 2; ++ka) {
        bf16x8 qf[4], pf[2];
        #pragma unroll
        for (int Mt = 0; Mt < 4; ++Mt)
            qf[Mt] = *(const bf16x8*)(qk + (size_t)(rt * 128 + wr * 64 + Mt * 16 + l15) * 128 + ka * 32 + g * 8);
        #pragma unroll
        for (int Nt = 0; Nt < 2; ++Nt) {
            int c = cb * 128 + wcol * 32 + Nt * 16 + l15;
            pf[Nt] = *(const bf16x8*)(ptb + (size_t)rt * 32768 + c * 64 + ka * 32 + g * 8);
        }
        #pragma unroll
        for (int Mt = 0; Mt < 4; ++Mt)
            #pragma unroll
            for (int Nt = 0; Nt < 2; ++Nt)
                acc[Mt][Nt] = __builtin_amdgcn_mfma_f32_16x16x32_bf16(qf[Mt], pf[Nt], acc[Mt][Nt], 0, 0, 0);
    }

    __syncthreads();

    // ---- PV diag: acc += S(128x128) @ V_diag(128 s x cols) ----
    #pragma unroll
    for (int ks = 0; ks < 4; ++ks) {
        bf16x8 sf[4], vf[2];
        #pragma unroll
        for (int Mt = 0; Mt < 4; ++Mt) {
            int row = wr * 64 + Mt * 16 + l15;
            int slot = (ks * 4 + g) ^ (row & 15);
            sf[Mt] = *(const bf16x8*)&Slds[row * 128 + slot * 8];
        }
        #pragma unroll
        for (int Nt = 0; Nt < 2; ++Nt) {
            int c = cb * 128 + wcol * 32 + Nt * 16 + l15;
            vf[Nt] = *(const bf16x8*)(vt + (size_t)c * TT + rt * 128 + ks * 32 + g * 8);
        }
        #pragma unroll
        for (int Mt = 0; Mt < 4; ++Mt)
            #pragma unroll
            for (int Nt = 0; Nt < 2; ++Nt)
                acc[Mt][Nt] = __builtin_amdgcn_mfma_f32_16x16x32_bf16(sf[Mt], vf[Nt], acc[Mt][Nt], 0, 0, 0);
    }

    // ---- epilogue: out = x + acc ----
    #pragma unroll
    for (int Mt = 0; Mt < 4; ++Mt) {
        #pragma unroll
        for (int Nt = 0; Nt < 2; ++Nt) {
            int col = cb * 128 + wcol * 32 + Nt * 16 + l15;
            #pragma unroll
            for (int jj = 0; jj < 4; ++jj) {
                int row = rt * 128 + wr * 64 + Mt * 16 + g * 4 + jj;
                out[(size_t)row * 512 + col] = x[(size_t)row * 512 + col] + acc[Mt][Nt][jj];
            }
        }
    }
}

extern "C" void kernel_launch(void* const* d_in, const int* in_sizes, int n_in,
                              void* d_out, int out_size, void* d_ws, size_t ws_size,
                              hipStream_t stream) {
    (void)in_sizes; (void)n_in; (void)out_size; (void)ws_size;
    const float* x    = (const float*)d_in[0];
    const float* xe   = (const float*)d_in[1];
    const float* lns  = (const float*)d_in[2];
    const float* lnb  = (const float*)d_in[3];
    const float* Wq   = (const float*)d_in[4];
    const float* Wk   = (const float*)d_in[5];
    const float* Wv   = (const float*)d_in[6];
    float* out = (float*)d_out;
    char* ws = (char*)d_ws;

    size_t off_xx   = 0;                                    // bf16 [8192][512]   8 MB
    size_t off_qk   = off_xx   + (size_t)TT * CC * 2;       // bf16 [8192][128]   2 MB
    size_t off_wqkt = off_qk   + (size_t)TT * 128 * 2;      // bf16 [128][512]
    size_t off_wvt  = off_wqkt + (size_t)128 * 512 * 2;     // bf16 [512][512]
    size_t off_vt   = off_wvt  + (size_t)512 * 512 * 2;     // bf16 [512][8192]   8 MB
    size_t off_xeb  = off_vt   + (size_t)TT * CC * 2;       // bf16 [8192][512]   8 MB
    size_t off_kt   = off_xeb  + (size_t)TT * CC * 2;       // bf16 [64][8192]    1 MB
    size_t off_h    = off_kt   + (size_t)64 * TT * 2;       // f32  [64][512][64]  8.4 MB
    size_t off_as   = off_h    + (size_t)64 * 32768 * 4;    // f32  [8][32768]     1 MB
    size_t off_ptb  = off_as   + (size_t)8 * 32768 * 4;     // bf16 [64][512][64]  4.2 MB

    u16* xx   = (u16*)(ws + off_xx);
    u16* qk   = (u16*)(ws + off_qk);
    u16* wqkt = (u16*)(ws + off_wqkt);
    u16* wvt  = (u16*)(ws + off_wvt);
    u16* vt   = (u16*)(ws + off_vt);
    u16* xeb  = (u16*)(ws + off_xeb);
    u16* kt   = (u16*)(ws + off_kt);
    float* H  = (float*)(ws + off_h);
    float* As = (float*)(ws + off_as);
    u16* ptb  = (u16*)(ws + off_ptb);

    const size_t qkv_lds = 65536;   // 64 KB

    hipLaunchKernelGGL(lnw_kernel,      dim3(5376), dim3(256), 0, stream,
                       x, lns, lnb, Wq, Wk, Wv, xe, xx, wqkt, wvt, xeb);
    hipLaunchKernelGGL(qkv_gemm_kernel, dim3(512),  dim3(512), qkv_lds, stream,
                       xx, wqkt, xeb, wvt, qk, kt, vt);
    hipLaunchKernelGGL(gkv_kernel,      dim3(256),  dim3(512), 0, stream, vt, kt, H);
    hipLaunchKernelGGL(scanA_kernel,    dim3(1024), dim3(256), 0, stream, H, As);
    hipLaunchKernelGGL(scanB_kernel,    dim3(1024), dim3(256), 0, stream, H, As, ptb);
    hipLaunchKernelGGL(out_kernel,      dim3(256),  dim3(512), 0, stream, qk, ptb, vt, x, out);
}